// Round 14
// baseline (232.015 us; speedup 1.0000x reference)
//
#include <hip/hip_runtime.h>
#include <hip/hip_bf16.h>

// ---------------- problem constants ----------------
#define B_TOTAL   32768
#define L_SITES   256
#define N_MID     254        // L-2 middle sites
#define HALF_PI_F 1.57079632679489662f
#define EPS_NORM  1e-8f

// ---------------- ws layout (float/dword slots) ----------------
// [WS_FRAG .. +520191]  A-operand fragment table: 254 steps x 8 frags x 64 lanes x 4 dwords
//                       frag q = h*4 + kh*2 + p  (h: c-half, kh: feature, p: 0=hi,1=lo)
//                       contraction axis PI-PERMUTED (k-slot (quad,j) holds
//                       a = (j<4 ? quad*4+j : 16+quad*4+j-4)) so the swapped-MFMA
//                       output feeds the next step with no transpose.
// [WS_C0   .. +63]      core0 fp32  [f][32]
// [WS_CN   .. +639]     coreN fp32  [f][a][10]
// [WS_X    .. +8388607] xT fp32 [L][B]  (transposed)
// [WS_FLAG]             u32 flag: 1 = inputs are bf16, 0 = fp32
#define WS_FRAG 0
#define WS_C0   520192
#define WS_CN   520256
#define WS_X    520896
#define WS_FLAG 8909504

typedef short bf16x8 __attribute__((ext_vector_type(8)));
typedef float f32x4  __attribute__((ext_vector_type(4)));

// pi-permutation of the contraction axis (k-slot -> actual a index)
__device__ __host__ __forceinline__ int pi_perm(int quad, int j) {
    return (j < 4) ? (quad * 4 + j) : (16 + quad * 4 + (j - 4));
}

__device__ __forceinline__ unsigned short f2bf(float f) {
    unsigned u = __builtin_bit_cast(unsigned, f);
    u += 0x7FFFu + ((u >> 16) & 1u);          // RNE
    return (unsigned short)(u >> 16);
}
__device__ __forceinline__ float bf2f(unsigned short h) {
    unsigned u = ((unsigned)h) << 16;
    return __builtin_bit_cast(float, u);
}
__device__ __forceinline__ bf16x8 asbf(uint4 u) {
    return __builtin_bit_cast(bf16x8, u);
}
// polynomial sincos for sin(pi/2 x), cos(pi/2 x), x in [0,1].
// Taylor through x^11 / x^12: truncation <= 6e-8. Verified passing in r11.
__device__ __forceinline__ void psincos(float x, float* s, float* c) {
    float u = x * x;
    float sp = fmaf(u, -3.5988432352121e-6f, 1.6044118478736e-4f);
    sp = fmaf(u, sp, -4.6817541353187e-3f);
    sp = fmaf(u, sp, 7.9692626246167e-2f);
    sp = fmaf(u, sp, -6.4596409750625e-1f);
    sp = fmaf(u, sp, 1.5707963267949f);
    *s = x * sp;
    float cp = fmaf(u, 4.7108749076366e-7f, -2.5202042373061e-5f);
    cp = fmaf(u, cp, 9.1926027483943e-4f);
    cp = fmaf(u, cp, -2.0863480763353e-2f);
    cp = fmaf(u, cp, 2.5366950790105e-1f);
    cp = fmaf(u, cp, -1.2337005501362f);
    *c = fmaf(u, cp, 1.0f);
}
// packed RNE f32x2 -> bf16x2 (lowers to v_cvt_pk_bf16_f32)
__device__ __forceinline__ unsigned pkbf2(float a, float b) {
    float2 p; p.x = a; p.y = b;
    __hip_bfloat162 h2 = __float22bfloat162_rn(p);
    unsigned u;
    __builtin_memcpy(&u, &h2, 4);
    return u;                                  // a in bits 0..15, b in 16..31
}
// split 8 fp32 into hi/lo bf16 fragments via packed cvt (RNE, proven)
__device__ __forceinline__ void split8(const float* v, bf16x8& hi, bf16x8& lo) {
    uint4 H, L;
    unsigned* hp = (unsigned*)&H;
    unsigned* lp = (unsigned*)&L;
    #pragma unroll
    for (int d = 0; d < 4; ++d) {
        float a = v[2 * d], b = v[2 * d + 1];
        unsigned hb = pkbf2(a, b);
        float h0 = __builtin_bit_cast(float, hb << 16);
        float h1 = __builtin_bit_cast(float, hb & 0xFFFF0000u);
        hp[d] = hb;
        lp[d] = pkbf2(a - h0, b - h1);         // exact residuals
    }
    hi = __builtin_bit_cast(bf16x8, H);
    lo = __builtin_bit_cast(bf16x8, L);
}
// per-wave input-dtype flag: bf16 pairs always have low16 < 0x4000
__device__ __forceinline__ bool detect_bf16(const unsigned* x_raw, int lane) {
    unsigned v = x_raw[lane];
    return __ballot((v & 0xFFFFu) >= 0x4000u) == 0ull;
}
// async global -> LDS DMA, 16 B/lane (dest = wave-uniform base + lane*16).
// r3 precedent: this exact helper ran CORRECT (r3 passed; it was only slow).
__device__ __forceinline__ void dma16(const uint4* g, uint4* l) {
    __builtin_amdgcn_global_load_lds(
        (const __attribute__((address_space(1))) unsigned*)g,
        (__attribute__((address_space(3))) unsigned*)l, 16, 0, 0);
}

// ---------------- fused aux kernel (r7, unchanged, verified) ----------------
__global__ __launch_bounds__(256)
void aux_all(const void* __restrict__ x_in, const void* __restrict__ c0_in,
             const void* __restrict__ am_in, const void* __restrict__ cn_in,
             float* __restrict__ ws) {
    const int lane = threadIdx.x & 63;
    const bool bf = detect_bf16((const unsigned*)x_in, lane);
    const int b = blockIdx.x;

    if (b < 2048) {
        __shared__ float tile[64][65];          // tile[b_local][l_local], +1 pad
        const int bb = (b & 511) * 64;
        const int ll = (b >> 9) * 64;
        if (!bf) {
            const float4* x4 = (const float4*)x_in;   // row = 64 float4
            const int tr = threadIdx.x >> 4;    // 0..15
            const int q  = threadIdx.x & 15;    // 0..15
            #pragma unroll
            for (int u = 0; u < 4; ++u) {
                int row = tr + u * 16;
                float4 v = x4[(size_t)(bb + row) * (L_SITES / 4) + (ll / 4) + q];
                tile[row][q * 4 + 0] = v.x;
                tile[row][q * 4 + 1] = v.y;
                tile[row][q * 4 + 2] = v.z;
                tile[row][q * 4 + 3] = v.w;
            }
        } else {
            const uint4* x8 = (const uint4*)x_in;     // row = 32 uint4 (8 bf16 each)
            const int tr = threadIdx.x >> 3;    // 0..31
            const int q  = threadIdx.x & 7;     // 0..7
            #pragma unroll
            for (int u = 0; u < 2; ++u) {
                int row = tr + u * 32;
                uint4 v = x8[(size_t)(bb + row) * (L_SITES / 8) + (ll / 8) + q];
                const unsigned short* e = (const unsigned short*)&v;
                #pragma unroll
                for (int k = 0; k < 8; ++k) tile[row][q * 8 + k] = bf2f(e[k]);
            }
        }
        __syncthreads();
        {
            const int tr = threadIdx.x >> 4;    // 0..15
            const int q  = threadIdx.x & 15;    // 0..15
            float4* o4 = (float4*)(ws + WS_X);
            #pragma unroll
            for (int u = 0; u < 4; ++u) {
                int site = tr + u * 16;         // l_local
                float4 v;
                v.x = tile[q * 4 + 0][site];
                v.y = tile[q * 4 + 1][site];
                v.z = tile[q * 4 + 2][site];
                v.w = tile[q * 4 + 3][site];
                o4[((size_t)(ll + site) * B_TOTAL + bb) / 4 + q] = v;
            }
        }
    } else if (b < 2048 + N_MID) {
        const int t = b - 2048;
        __shared__ float amS[2][32][33];        // [f][a][m], +1 pad vs 4-way conflicts
        if (!bf) {
            const float* src = (const float*)am_in + (size_t)t * 2048;
            for (int idx = threadIdx.x; idx < 2048; idx += 256) {
                amS[idx >> 10][(idx >> 5) & 31][idx & 31] = src[idx];
            }
        } else {
            const unsigned short* src = (const unsigned short*)am_in + (size_t)t * 2048;
            for (int idx = threadIdx.x; idx < 2048; idx += 256) {
                amS[idx >> 10][(idx >> 5) & 31][idx & 31] = bf2f(src[idx]);
            }
        }
        __syncthreads();
        #pragma unroll
        for (int u = 0; u < 2; ++u) {
            const int oi = threadIdx.x + 256 * u;   // 0..511
            const int q  = oi >> 6;                 // frag 0..7
            const int l  = oi & 63;                 // lane
            const int h  = q >> 2;
            const int kh = (q >> 1) & 1;
            const int p  = q & 1;
            const int m  = h * 16 + (l & 15);
            const int kb = (l >> 4) * 8;
            unsigned dw[4];
            #pragma unroll
            for (int d = 0; d < 4; ++d) {
                unsigned e01[2];
                #pragma unroll
                for (int s = 0; s < 2; ++s) {
                    int k = kb + 2 * d + s;         // k-slot 0..31
                    int a = pi_perm(k >> 3, k & 7); // PI-permuted contraction index
                    float v = amS[kh][a][m];
                    unsigned short hi = f2bf(v);
                    e01[s] = (p == 0) ? hi : f2bf(v - bf2f(hi));
                }
                dw[d] = e01[0] | (e01[1] << 16);
            }
            uint4 o; o.x = dw[0]; o.y = dw[1]; o.z = dw[2]; o.w = dw[3];
            ((uint4*)ws)[(size_t)(t * 8 + q) * 64 + l] = o;
        }
    } else {
        for (int i = threadIdx.x; i < 640; i += 256) {
            if (i < 64)
                ws[WS_C0 + i] = bf ? bf2f(((const unsigned short*)c0_in)[i])
                                   : ((const float*)c0_in)[i];
            ws[WS_CN + i] = bf ? bf2f(((const unsigned short*)cn_in)[i])
                               : ((const float*)cn_in)[i];
        }
        if (threadIdx.x == 0)
            *(unsigned*)(ws + WS_FLAG) = bf ? 1u : 0u;
    }
}

// ---------------- main chain kernel ----------------
// r11 step math (swapped-operand chain, post-scale factorization, psincos —
// all verified passing). THIS ROUND (resubmit of r13 — infra failure, never
// ran): block-shared EPOCH staging.
// Diagnosis: r5's natural experiment (half the steps, double per-step loads,
// same total traffic -> same time) proves the chain is VMEM-THROUGHPUT-bound:
// 8 waves/CU x 8KB/step = 64KB/CU/step through TA/L1/L2 is the ~800cyc wall.
// The 4 waves of a block read IDENTICAL fragments -> stage once per block:
//  * epochs of 4 steps: all 4 waves cooperatively DMA 32KB (8 gload_lds each,
//    no destination registers -> immune to the r9-r12 asm-output corruption;
//    the builtin is visible to the compiler's waitcnt pass).
//  * 2-buffer LDS ring (64KB, m132 precedent), one __syncthreads per epoch
//    (64 total vs r3's 254 -> no per-step convoy; its drain is cheap since
//    the waited DMAs are ~4 steps old).
//  * TA/L2 traffic per CU-step: 64KB -> 16KB (4x cut).
//  * fragments consumed as contiguous ds_read_b128; compiler pipelines them
//    into the MFMAs with fine lgkmcnt (m97 evidence).
__global__ __launch_bounds__(256, 2)
void mps_mfma(const float* __restrict__ ws, void* __restrict__ out) {
    __shared__ uint4 FR[2][2048];   // 2 epoch buffers x (4 steps x 8 frags x 64 lanes)
    const int lane = threadIdx.x & 63;
    const int w    = threadIdx.x >> 6;
    const int r    = lane & 15;
    const int quad = lane >> 4;
    const int b0   = (blockIdx.x * 4 + w) * 16;
    const float* __restrict__ xT = ws + WS_X;
    const uint4* __restrict__ BF = (const uint4*)ws;   // WS_FRAG = 0
    const int i = b0 + r;

// DMA one epoch (4 steps x 8 frags) into buffer B; wave w covers frags 2w,2w+1.
// Epoch 63 touches steps 254/255: in-ws garbage (C0/CN region), never consumed.
#define DMA_EPOCH(E, B)                                                            \
    {                                                                              \
        _Pragma("unroll")                                                          \
        for (int k_ = 0; k_ < 4; ++k_) {                                           \
            const uint4* S_ = BF + (((size_t)(4 * (E) + k_) * 8 + 2 * w) * 64) + lane; \
            dma16(S_,      &FR[B][k_ * 512 + (2 * w) * 64]);                       \
            dma16(S_ + 64, &FR[B][k_ * 512 + (2 * w) * 64 + 64]);                  \
        }                                                                          \
    }

// one chain step: split M once -> 12 MFMA (4 indep 3-chains) -> post-scale
// combine with (CT,ST) -> optional norm.  (bit-identical to r7/r11)
#define DO_STEP(CT, ST, Q0, Q1, Q2, Q3, Q4, Q5, Q6, Q7, DONORM)                    \
    {                                                                              \
        bf16x8 mh, ml;                                                             \
        split8(mm, mh, ml);                                                        \
        const f32x4 z = {0.f, 0.f, 0.f, 0.f};                                      \
        __builtin_amdgcn_s_setprio(1);                                             \
        f32x4 p00 = __builtin_amdgcn_mfma_f32_16x16x32_bf16(asbf(Q0), mh, z, 0, 0, 0);    \
        f32x4 p01 = __builtin_amdgcn_mfma_f32_16x16x32_bf16(asbf(Q2), mh, z, 0, 0, 0);    \
        f32x4 p10 = __builtin_amdgcn_mfma_f32_16x16x32_bf16(asbf(Q4), mh, z, 0, 0, 0);    \
        f32x4 p11 = __builtin_amdgcn_mfma_f32_16x16x32_bf16(asbf(Q6), mh, z, 0, 0, 0);    \
        p00 = __builtin_amdgcn_mfma_f32_16x16x32_bf16(asbf(Q1), mh, p00, 0, 0, 0); \
        p01 = __builtin_amdgcn_mfma_f32_16x16x32_bf16(asbf(Q3), mh, p01, 0, 0, 0); \
        p10 = __builtin_amdgcn_mfma_f32_16x16x32_bf16(asbf(Q5), mh, p10, 0, 0, 0); \
        p11 = __builtin_amdgcn_mfma_f32_16x16x32_bf16(asbf(Q7), mh, p11, 0, 0, 0); \
        p00 = __builtin_amdgcn_mfma_f32_16x16x32_bf16(asbf(Q0), ml, p00, 0, 0, 0); \
        p01 = __builtin_amdgcn_mfma_f32_16x16x32_bf16(asbf(Q2), ml, p01, 0, 0, 0); \
        p10 = __builtin_amdgcn_mfma_f32_16x16x32_bf16(asbf(Q4), ml, p10, 0, 0, 0); \
        p11 = __builtin_amdgcn_mfma_f32_16x16x32_bf16(asbf(Q6), ml, p11, 0, 0, 0); \
        __builtin_amdgcn_s_setprio(0);                                             \
        _Pragma("unroll")                                                          \
        for (int j = 0; j < 4; ++j) {                                              \
            mm[j]     = fmaf((ST), p01[j], (CT) * p00[j]);                         \
            mm[4 + j] = fmaf((ST), p11[j], (CT) * p10[j]);                         \
        }                                                                          \
        if (DONORM) {                                                              \
            float ss = 0.f;                                                        \
            _Pragma("unroll")                                                      \
            for (int j = 0; j < 8; ++j) ss = fmaf(mm[j], mm[j], ss);               \
            ss += __shfl_xor(ss, 16);                                              \
            ss += __shfl_xor(ss, 32);                                              \
            float kk = 1.0f / (sqrtf(ss) + EPS_NORM);                              \
            _Pragma("unroll")                                                      \
            for (int j = 0; j < 8; ++j) mm[j] *= kk;                               \
        }                                                                          \
    }

    // ---- prologue: DMA epoch 0 first (M0 compute covers its flight) ----
    DMA_EPOCH(0, 0)

    // ---- M0 in pi-layout: mm[j] = M0[b=r][a=pi(quad,j)] ----
    float mm[8];
    {
        float x0 = xT[i];
        float sn, cs; psincos(x0, &sn, &cs);
        const float* c0 = ws + WS_C0;
        #pragma unroll
        for (int j = 0; j < 8; ++j) {
            int a = pi_perm(quad, j);
            mm[j] = cs * c0[a] + sn * c0[32 + a];
        }
    }
    float ct, st;                                       // factors for step 0 (site 1)
    { float xc = xT[(size_t)B_TOTAL + i]; psincos(xc, &st, &ct); }
    float xn = xT[(size_t)2 * B_TOTAL + i];             // x row for step 1 factors

    #pragma unroll 1
    for (int e = 0; e < 64; ++e) {                      // epochs of 4 steps
        // publish buffer e: our own DMAs (issued >= 1 epoch ago) drained by
        // __syncthreads' vmcnt(0), then all waves see the staged fragments.
        __syncthreads();
        if (e + 1 < 64) DMA_EPOCH(e + 1, (e + 1) & 1)   // stage next epoch
        const uint4* EB = &FR[e & 1][0];

        #pragma unroll
        for (int k = 0; k < 4; ++k) {
            const int s = 4 * e + k;
            if (s < N_MID) {                            // uniform guard (epoch 63 tail)
                const uint4* F = EB + k * 512;
                uint4 f0 = F[lane];        uint4 f1 = F[64 + lane];
                uint4 f2 = F[128 + lane];  uint4 f3 = F[192 + lane];
                uint4 f4 = F[256 + lane];  uint4 f5 = F[320 + lane];
                uint4 f6 = F[384 + lane];  uint4 f7 = F[448 + lane];

                float ctn, stn; psincos(xn, &stn, &ctn);    // factors for step s+1
                int xr = s + 3; if (xr > 255) xr = 255;
                float xn2 = xT[(size_t)xr * B_TOTAL + i];   // x row for step s+2

                DO_STEP(ct, st, f0, f1, f2, f3, f4, f5, f6, f7,
                        (((s & 7) == 7) || (s == N_MID - 1)))

                ct = ctn; st = stn; xn = xn2;
            }
        }
    }
#undef DO_STEP
#undef DMA_EPOCH

    // ---- readout: logits[r][c] = sum_a M[r][a]*(cN*KN0[a,c] + sN*KN1[a,c]) ----
    {
        float xN = xT[(size_t)(L_SITES - 1) * B_TOTAL + i];
        float sN, cN; psincos(xN, &sN, &cN);
        const float* kn = ws + WS_CN;        // [f][a][10]
        float acc[10];
        #pragma unroll
        for (int c = 0; c < 10; ++c) acc[c] = 0.f;
        #pragma unroll
        for (int j = 0; j < 8; ++j) {
            int a = pi_perm(quad, j);
            float Ma = mm[j];
            #pragma unroll
            for (int c = 0; c < 10; ++c) {
                float fin = cN * kn[a * 10 + c] + sN * kn[320 + a * 10 + c];
                acc[c] = fmaf(Ma, fin, acc[c]);
            }
        }
        #pragma unroll
        for (int c = 0; c < 10; ++c) {
            acc[c] += __shfl_xor(acc[c], 16);
            acc[c] += __shfl_xor(acc[c], 32);
        }
        const unsigned bf = *(const unsigned*)(ws + WS_FLAG);
        if (quad == 0) {
            if (bf) {
                __hip_bfloat16* o = (__hip_bfloat16*)out;
                #pragma unroll
                for (int c = 0; c < 10; ++c)
                    o[(size_t)(b0 + r) * 10 + c] = __float2bfloat16(acc[c]);
            } else {
                float* o = (float*)out;
                #pragma unroll
                for (int c = 0; c < 10; ++c)
                    o[(size_t)(b0 + r) * 10 + c] = acc[c];
            }
        }
    }
}

// ---------------- launch ----------------
extern "C" void kernel_launch(void* const* d_in, const int* in_sizes, int n_in,
                              void* d_out, int out_size, void* d_ws, size_t ws_size,
                              hipStream_t stream) {
    float* ws = (float*)d_ws;
    aux_all<<<2048 + N_MID + 1, 256, 0, stream>>>(d_in[0], d_in[1], d_in[2], d_in[3], ws);
    // 512 blocks x 4 waves x 16 samples = 32768 samples; 2048 waves = 2 waves/SIMD
    mps_mfma<<<512, 256, 0, stream>>>(ws, d_out);
}